// Round 10
// baseline (237.562 us; speedup 1.0000x reference)
//
#include <hip/hip_runtime.h>
#include <math.h>

#define F 128
#define DEG 5
#define TM 128
#define MAXNORM_D 0.996          // (1 - 4e-3)/sqrt(c), c=1
#define MIN_NORM_D 1e-15

typedef float f32x4 __attribute__((ext_vector_type(4)));
typedef short s16x8 __attribute__((ext_vector_type(8)));
typedef _Float16 f16x4 __attribute__((ext_vector_type(4)));

__device__ inline double atanh_clip(double v) {
    v = fmin(fmax(v, -1.0 + 1e-7), 1.0 - 1e-7);
    return atanh(v);
}

// split fp32 v -> hi bf16 (round-half-up) + lo bf16 (trunc of exact residual); pack pairs
__device__ inline void split2(float v0, float v1, unsigned& hi, unsigned& lo) {
    unsigned b0 = __float_as_uint(v0), b1 = __float_as_uint(v1);
    unsigned h0 = (b0 + 0x8000u) >> 16;
    unsigned h1 = (b1 + 0x8000u) >> 16;
    float l0 = v0 - __uint_as_float(h0 << 16);
    float l1 = v1 - __uint_as_float(h1 << 16);
    hi = h0 | (h1 << 16);
    lo = (__float_as_uint(l0) >> 16) | (__float_as_uint(l1) & 0xFFFF0000u);
}

// ---------------------------------------------------------------- K0: pack W into B-fragment order  +  dst histogram
__global__ __launch_bounds__(256) void k_ph(const float* __restrict__ W,
                                            uint4* __restrict__ Wfh, uint4* __restrict__ Wfl,
                                            const int* __restrict__ edge, int* __restrict__ cnt, int E) {
    if (blockIdx.x < 8) {
        int tid = blockIdx.x * 256 + threadIdx.x;   // 0..2047
        int c = tid >> 9;                           // 0..3
        int tp = (tid >> 6) & 7;
        int lane = tid & 63;
        int f = tp * 16 + (lane & 15);
        int k = c * 32 + (lane >> 4) * 8;
        const float* wp = W + f * F + k;
        unsigned h[4], l[4];
#pragma unroll
        for (int p = 0; p < 4; p++) split2(wp[2 * p], wp[2 * p + 1], h[p], l[p]);
        Wfh[tid] = make_uint4(h[0], h[1], h[2], h[3]);
        Wfl[tid] = make_uint4(l[0], l[1], l[2], l[3]);
    } else {
        int stride = (gridDim.x - 8) * 256;
        for (int e = (blockIdx.x - 8) * 256 + threadIdx.x; e < E; e += stride)
            atomicAdd(&cnt[edge[E + e]], 1);
    }
}

// ---------------------------------------------------------------- K2: y = x @ W^T via split-bf16 MFMA
// NO-LDS VARIANT: B-fragments read DIRECTLY from global Wfh/Wfl (64 KB total, L2-hot in every
// XCD after first touch; lane-contiguous 1KB/instruction). No staging, no global_load_lds, no
// drain-coupled mid-kernel barriers -> every wave independent, latency hidden by plain TLP.
// (Rounds 2-9: every LDS-staged variant stuck at 40-54us on barrier tail-latency.)
// A-row fully hoisted (8 x 16B in flight). Accumulation order identical (c asc, tp asc).
// Epilogue: fused ssum2/wsum2 (banked global atomics) + fp16 pair-packed yh stores.
__global__ __launch_bounds__(512, 4) void k_gemm(const float* __restrict__ x,
                                                 const uint4* __restrict__ Wfh, const uint4* __restrict__ Wfl,
                                                 const int* __restrict__ cnt, _Float16* __restrict__ yh,
                                                 float* __restrict__ ssum2, float* __restrict__ wsum2, int N) {
    __shared__ float red_ss[F];
    __shared__ float red_ws[F];
    __shared__ int cntL[TM];

    int t = threadIdx.x;
    int lane = t & 63;
    int w = t >> 6;
    int n0 = blockIdx.x * TM;

    if (t < F) { red_ss[t] = 0.f; red_ws[t] = 0.f; }
    if (t < TM) { int n = n0 + t; cntL[t] = (n < N) ? cnt[n] : 0; }

    int row = n0 + w * 16 + (lane & 15);
    if (row > N - 1) row = N - 1;                 // clamp: no fault, masked in epilogue
    const float* xr = x + (size_t)row * F + (lane >> 4) * 8;

    // hoist the ENTIRE A row (8 x 16B in flight)
    float4 av0[4], av1[4];
#pragma unroll
    for (int c = 0; c < 4; c++) {
        av0[c] = *(const float4*)(xr + c * 32);
        av1[c] = *(const float4*)(xr + c * 32 + 4);
    }

    f32x4 acc[8];
#pragma unroll
    for (int i = 0; i < 8; i++) acc[i] = (f32x4){0.f, 0.f, 0.f, 0.f};

    // main loop: B-frags straight from L2; fully unrolled so loads pipeline ahead of use
#pragma unroll
    for (int c = 0; c < 4; c++) {
        unsigned h[4], l[4];
        split2(av0[c].x, av0[c].y, h[0], l[0]);
        split2(av0[c].z, av0[c].w, h[1], l[1]);
        split2(av1[c].x, av1[c].y, h[2], l[2]);
        split2(av1[c].z, av1[c].w, h[3], l[3]);
        s16x8 a_hi = __builtin_bit_cast(s16x8, make_uint4(h[0], h[1], h[2], h[3]));
        s16x8 a_lo = __builtin_bit_cast(s16x8, make_uint4(l[0], l[1], l[2], l[3]));
#pragma unroll
        for (int tp = 0; tp < 8; tp++) {
            s16x8 bh = __builtin_bit_cast(s16x8, Wfh[(c * 8 + tp) * 64 + lane]);
            s16x8 bl = __builtin_bit_cast(s16x8, Wfl[(c * 8 + tp) * 64 + lane]);
            acc[tp] = __builtin_amdgcn_mfma_f32_16x16x32_bf16(a_hi, bh, acc[tp], 0, 0, 0);
            acc[tp] = __builtin_amdgcn_mfma_f32_16x16x32_bf16(a_lo, bh, acc[tp], 0, 0, 0);
            acc[tp] = __builtin_amdgcn_mfma_f32_16x16x32_bf16(a_hi, bl, acc[tp], 0, 0, 0);
        }
    }

    __syncthreads();   // red_ss/red_ws zero-init + cntL visible (cheap: no big loads pending)

    int fb = lane & 15;
    int rg = lane >> 4;
    int odd = fb & 1;

    // fused ssum2/wsum2 (f32, pre-quantization)
#pragma unroll
    for (int tp = 0; tp < 8; tp++) {
        int f = tp * 16 + fb;
        float sv = 0.f, wv = 0.f;
#pragma unroll
        for (int r = 0; r < 4; r++) {
            int lr = w * 16 + rg * 4 + r;
            int n = n0 + lr;
            float v = acc[tp][r];
            if (n < N) {
                sv += v * v;
                wv += (float)cntL[lr] * v * v;
            }
        }
        sv += __shfl_xor(sv, 16, 64); sv += __shfl_xor(sv, 32, 64);
        wv += __shfl_xor(wv, 16, 64); wv += __shfl_xor(wv, 32, 64);
        if (lane < 16) {
            atomicAdd(&red_ss[f], sv);
            atomicAdd(&red_ws[f], wv);
        }
    }

    // fp16 store of yh (pair-packed dwords; each instruction covers full 64-B lines)
#pragma unroll
    for (int r = 0; r < 4; r++) {
        int n = n0 + w * 16 + rg * 4 + r;
        unsigned hb[8], ob[8], pk[8];
#pragma unroll
        for (int tp = 0; tp < 8; tp++) {
            _Float16 hv = (_Float16)acc[tp][r];
            hb[tp] = (unsigned)__builtin_bit_cast(unsigned short, hv);
        }
#pragma unroll
        for (int tp = 0; tp < 8; tp++) ob[tp] = (unsigned)__shfl_xor((int)hb[tp], 1, 64);
#pragma unroll
        for (int tp = 0; tp < 8; tp++)
            pk[tp] = odd ? (ob[tp] | (hb[tp] << 16)) : (hb[tp] | (ob[tp] << 16));
        if (n < N) {
            unsigned* bp = (unsigned*)(yh + (size_t)n * F + (fb & ~1));
#pragma unroll
            for (int i = 0; i < 4; i++) {
                int tp = 2 * i + odd;
                unsigned v = odd ? pk[2 * i + 1] : pk[2 * i];   // static indices only
                bp[tp * 8] = v;                                  // tp*16 halfs = tp*8 dwords
            }
        }
    }

    __syncthreads();
    if (t < F) {
        int bank = (blockIdx.x & 7) * F;
        atomicAdd(&ssum2[bank + t], red_ss[t]);
        atomicAdd(&wsum2[bank + t], red_ws[t]);
    }
}

// ---------------------------------------------------------------- K2b: all global scalar factors (f64)
__global__ __launch_bounds__(256) void k_scalars(const float* __restrict__ W, const float* __restrict__ a,
                                                 const float* __restrict__ ssum2, const float* __restrict__ wsum2,
                                                 float* __restrict__ s_arr, float* __restrict__ asrc,
                                                 float* __restrict__ adst, double* __restrict__ an_out) {
    int t = threadIdx.x;
    double av = (double)a[t];
    av *= av;
#pragma unroll
    for (int off = 32; off; off >>= 1) av += __shfl_down(av, off, 64);
    __shared__ double wred[4];
    if ((t & 63) == 0) wred[t >> 6] = av;
    __syncthreads();
    double an = fmax(sqrt(wred[0] + wred[1] + wred[2] + wred[3]), MIN_NORM_D);
    if (t == 0) an_out[0] = an;

    if (t < F) {
        float ss2f = 0.f, ws2f = 0.f;
#pragma unroll
        for (int b = 0; b < 8; b++) { ss2f += ssum2[b * F + t]; ws2f += wsum2[b * F + t]; }

        double wn2 = 0.0;
        for (int k = 0; k < F; k++) { double w = (double)W[t * F + k]; wn2 += w * w; }
        double wn = fmax(sqrt(wn2), MIN_NORM_D);
        double mxnf = fmax(sqrt((double)ss2f), MIN_NORM_D);
        double tt = tanh(mxnf / wn * atanh_clip(wn));
        double rn = fmax(tt, MIN_NORM_D);
        double pf = (rn > MAXNORM_D) ? MAXNORM_D / rn : 1.0;
        double pn = rn * pf;
        double s = (tt / mxnf) * pf * atanh_clip(pn) / pn;
        s_arr[t] = (float)s;

        double un_s = fmax(s * sqrt((double)DEG * (double)ss2f), MIN_NORM_D);
        double th_s = tanh(un_s);
        double rn2 = fmax(th_s, MIN_NORM_D);
        double pf2 = (rn2 > MAXNORM_D) ? MAXNORM_D / rn2 : 1.0;
        double q_s = s * (th_s / un_s) * pf2;
        asrc[t] = (float)((double)a[t] * q_s);

        double un_d = fmax(s * sqrt((double)ws2f), MIN_NORM_D);
        double th_d = tanh(un_d);
        double rn3 = fmax(th_d, MIN_NORM_D);
        double pf3 = (rn3 > MAXNORM_D) ? MAXNORM_D / rn3 : 1.0;
        double q_d = s * (th_d / un_d) * pf3;
        adst[t] = (float)((double)a[F + t] * q_d);
    }
}

// ---------------------------------------------------------------- K3: P[n]=dot(asrc,y[n,:]) Q[n]=dot(adst,y[n,:])
__global__ __launch_bounds__(256) void k_pq(const _Float16* __restrict__ yh, const float* __restrict__ asrc,
                                            const float* __restrict__ adst, float* __restrict__ P,
                                            float* __restrict__ Q, int N) {
    __shared__ float as4[F], ad4[F];
    int t = threadIdx.x;
    if (t < F) { as4[t] = asrc[t]; ad4[t] = adst[t]; }
    __syncthreads();
    int lane = t & 31;
    float4 av = *(const float4*)&as4[lane * 4];
    float4 bv = *(const float4*)&ad4[lane * 4];
    for (int nb = blockIdx.x * 8; nb < N; nb += gridDim.x * 8) {
        int n = nb + (t >> 5);
        if (n < N) {
            f16x4 hv = *(const f16x4*)&yh[(size_t)n * F + lane * 4];   // 32 lanes x 8B = 256B
            float4 yv = make_float4((float)hv[0], (float)hv[1], (float)hv[2], (float)hv[3]);
            float p = yv.x * av.x + yv.y * av.y + yv.z * av.z + yv.w * av.w;
            float q = yv.x * bv.x + yv.y * bv.y + yv.z * bv.z + yv.w * bv.w;
#pragma unroll
            for (int off = 16; off; off >>= 1) {
                p += __shfl_down(p, off, 32);
                q += __shfl_down(q, off, 32);
            }
            if (lane == 0) { P[n] = p; Q[n] = q; }
        }
    }
}

// ---------------------------------------------------------------- K4: mxn2 = sum_e (P[e/DEG]+Q[dst])^2  (f64)
__global__ __launch_bounds__(256) void k_edge(const int* __restrict__ edge, const float* __restrict__ P,
                                              const float* __restrict__ Q,
                                              double* __restrict__ mxn2, int E) {
    int t = threadIdx.x;
    double local = 0.0;
    for (int e0 = blockIdx.x * 256; e0 < E; e0 += gridDim.x * 256) {
        int e = e0 + t;
        if (e < E) {
            float v = P[e / DEG] + Q[edge[E + e]];
            local += (double)v * (double)v;
        }
    }
#pragma unroll
    for (int off = 32; off; off >>= 1) local += __shfl_down(local, off, 64);
    __shared__ double wsum[4];
    if ((t & 63) == 0) wsum[t >> 6] = local;
    __syncthreads();
    if (t == 0) atomicAdd(mxn2, wsum[0] + wsum[1] + wsum[2] + wsum[3]);
}

// ---------------------------------------------------------------- K5: fused weights + aggregate + epilogue
__global__ __launch_bounds__(256) void k_wagg(const int* __restrict__ edge, const _Float16* __restrict__ yh,
                                              const float* __restrict__ P, const float* __restrict__ Q,
                                              const double* __restrict__ an_p, const double* __restrict__ mxn2_p,
                                              const float* __restrict__ s_arr,
                                              float* __restrict__ out, int N, int E) {
    __shared__ float gS;
    int t = threadIdx.x;
    if (t == 0) {
        double an = an_p[0];
        double mxn = fmax(sqrt(mxn2_p[0]), MIN_NORM_D);
        double t2 = tanh(mxn / an * atanh_clip(an));
        double f2 = t2 / mxn;
        double rnp = fmax(t2, MIN_NORM_D);
        double pfp = (rnp > MAXNORM_D) ? MAXNORM_D / rnp : 1.0;
        double pnp = rnp * pfp;
        gS = (float)(f2 * pfp * atanh_clip(pnp) / pnp);
    }
    __syncthreads();
    float g = gS;

    int lane = t & 63;
    int sub = lane & 7;
    int slot = t >> 3;                 // node slot within block, 0..31
    int gbase = lane & ~7;             // first lane of this 8-lane group

    int n = blockIdx.x * 32 + slot;
    bool active = (n < N);
    int nc = active ? n : N - 1;       // clamp: no fault, store masked

    // phase A: lanes sub<5 compute the edge weight + dst offset
    float w = 0.f; int d = 0;
    if (sub < DEG) {
        int e = nc * DEG + sub;
        int dn = edge[E + e];
        float v = P[nc] + Q[dn];       // == ee_pre[e], same arithmetic as before
        float xg = g * v;
        float gl = 0.5f * xg * (1.f + erff(xg * 0.70710678f));
        w = expf(-gl);
        d = dn << 7;                   // element offset (128 halfs per row)
    }
    float wj[DEG]; int dj[DEG];
#pragma unroll
    for (int j = 0; j < DEG; j++) {
        wj[j] = __shfl(w, gbase + j, 64);
        dj[j] = __shfl(d, gbase + j, 64);
    }
    float rowsum = wj[0] + wj[1] + wj[2] + wj[3] + wj[4];
    float inv = 1.f / rowsum;

    // phase B: fp16 gather + weighted accumulate (same j-order as before)
    float4 acc[4];
#pragma unroll
    for (int p = 0; p < 4; p++) acc[p] = make_float4(0.f, 0.f, 0.f, 0.f);
#pragma unroll
    for (int j = 0; j < DEG; j++) {
        const _Float16* yp = yh + dj[j] + sub * 4;
        float wv = wj[j];
#pragma unroll
        for (int p = 0; p < 4; p++) {
            f16x4 hv = *(const f16x4*)(yp + p * 32);
            acc[p].x = fmaf(wv, (float)hv[0], acc[p].x);
            acc[p].y = fmaf(wv, (float)hv[1], acc[p].y);
            acc[p].z = fmaf(wv, (float)hv[2], acc[p].z);
            acc[p].w = fmaf(wv, (float)hv[3], acc[p].w);
        }
    }

    // epilogue: elu -> expmap0 -> proj (norm reduced over the 8-lane group)
    float4 s4[4];
#pragma unroll
    for (int p = 0; p < 4; p++) s4[p] = *(const float4*)&s_arr[p * 32 + sub * 4];

    float4 el[4];
    float ss = 0.f;
#pragma unroll
    for (int p = 0; p < 4; p++) {
        float h;
        h = s4[p].x * acc[p].x * inv; el[p].x = (h > 0.f) ? h : expm1f(h);
        h = s4[p].y * acc[p].y * inv; el[p].y = (h > 0.f) ? h : expm1f(h);
        h = s4[p].z * acc[p].z * inv; el[p].z = (h > 0.f) ? h : expm1f(h);
        h = s4[p].w * acc[p].w * inv; el[p].w = (h > 0.f) ? h : expm1f(h);
        ss += el[p].x * el[p].x + el[p].y * el[p].y + el[p].z * el[p].z + el[p].w * el[p].w;
    }
    ss += __shfl_xor(ss, 1, 64);
    ss += __shfl_xor(ss, 2, 64);
    ss += __shfl_xor(ss, 4, 64);

    float un = fmaxf(sqrtf(ss), 1e-15f);
    float th = tanhf(un);
    float sc = th / un;                   // expmap0
    float rn = fmaxf(th, 1e-15f);
    if (rn > 0.996f) sc *= 0.996f / rn;   // proj
    if (active) {
        float* op = out + (size_t)n * F + sub * 4;
#pragma unroll
        for (int p = 0; p < 4; p++) {
            float4 o = make_float4(el[p].x * sc, el[p].y * sc, el[p].z * sc, el[p].w * sc);
            *(float4*)(op + p * 32) = o;
        }
    }
}

extern "C" void kernel_launch(void* const* d_in, const int* in_sizes, int n_in,
                              void* d_out, int out_size, void* d_ws, size_t ws_size,
                              hipStream_t stream) {
    const float* x = (const float*)d_in[0];
    const int* edge = (const int*)d_in[1];
    const float* W = (const float*)d_in[2];
    const float* a = (const float*)d_in[3];
    float* out = (float*)d_out;
    int N = in_sizes[0] / F;
    int E = in_sizes[1] / 2;

    char* ws = (char*)d_ws;
    size_t off = 0;
    _Float16* yh = (_Float16*)(ws + off); off += (size_t)N * F * 2;   // fp16 y (only copy)
    uint4* Wfh = (uint4*)(ws + off);     off += 2048 * 16;            // 32 KB B-frag hi
    uint4* Wfl = (uint4*)(ws + off);     off += 2048 * 16;            // 32 KB B-frag lo
    float* P = (float*)(ws + off);       off += (size_t)N * 4;
    float* Q = (float*)(ws + off);       off += (size_t)N * 4;
    char* zbase = ws + off;
    int* cnt = (int*)(ws + off);         off += (size_t)N * 4;
    float* ssum2 = (float*)(ws + off);   off += 8 * F * 4;            // 8 banks
    float* wsum2 = (float*)(ws + off);   off += 8 * F * 4;            // 8 banks
    double* mxn2 = (double*)(ws + off);  off += 8;
    size_t zlen = (size_t)((ws + off) - zbase);
    double* an_p = (double*)(ws + off);  off += 8;
    float* s_arr = (float*)(ws + off);   off += 512;
    float* asrc = (float*)(ws + off);    off += 512;
    float* adst = (float*)(ws + off);    off += 512;

    hipMemsetAsync(zbase, 0, zlen, stream);
    k_ph<<<8 + 1024, 256, 0, stream>>>(W, Wfh, Wfl, edge, cnt, E);
    k_gemm<<<(N + TM - 1) / TM, 512, 0, stream>>>(x, Wfh, Wfl, cnt, yh, ssum2, wsum2, N);
    k_scalars<<<1, 256, 0, stream>>>(W, a, ssum2, wsum2, s_arr, asrc, adst, an_p);
    k_pq<<<2048, 256, 0, stream>>>(yh, asrc, adst, P, Q, N);
    k_edge<<<1024, 256, 0, stream>>>(edge, P, Q, mxn2, E);
    k_wagg<<<(N + 31) / 32, 256, 0, stream>>>(edge, yh, P, Q, an_p, mxn2, s_arr, out, N, E);
}

// Round 11
// 210.319 us; speedup vs baseline: 1.1295x; 1.1295x over previous
//
#include <hip/hip_runtime.h>
#include <math.h>

#define F 128
#define DEG 5
#define TM 256                   // per block: two 128-row subtiles sharing one W staging
#define MAXNORM_D 0.996          // (1 - 4e-3)/sqrt(c), c=1
#define MIN_NORM_D 1e-15

typedef float f32x4 __attribute__((ext_vector_type(4)));
typedef short s16x8 __attribute__((ext_vector_type(8)));
typedef _Float16 f16x4 __attribute__((ext_vector_type(4)));

__device__ inline double atanh_clip(double v) {
    v = fmin(fmax(v, -1.0 + 1e-7), 1.0 - 1e-7);
    return atanh(v);
}

__device__ inline void load_lds16(const void* g, void* l) {
    __builtin_amdgcn_global_load_lds((const __attribute__((address_space(1))) void*)g,
                                     (__attribute__((address_space(3))) void*)l, 16, 0, 0);
}

// split fp32 v -> hi bf16 (round-half-up) + lo bf16 (trunc of exact residual); pack pairs
__device__ inline void split2(float v0, float v1, unsigned& hi, unsigned& lo) {
    unsigned b0 = __float_as_uint(v0), b1 = __float_as_uint(v1);
    unsigned h0 = (b0 + 0x8000u) >> 16;
    unsigned h1 = (b1 + 0x8000u) >> 16;
    float l0 = v0 - __uint_as_float(h0 << 16);
    float l1 = v1 - __uint_as_float(h1 << 16);
    hi = h0 | (h1 << 16);
    lo = (__float_as_uint(l0) >> 16) | (__float_as_uint(l1) & 0xFFFF0000u);
}

// full K (4 chunks) of the 3-term split-MFMA product from staged LDS W
__device__ inline void mfma_tile(const float4* av0, const float4* av1,
                                 const uint4* Wh_s, const uint4* Wl_s,
                                 int lane, f32x4* acc) {
#pragma unroll
    for (int c = 0; c < 4; c++) {
        unsigned h[4], l[4];
        split2(av0[c].x, av0[c].y, h[0], l[0]);
        split2(av0[c].z, av0[c].w, h[1], l[1]);
        split2(av1[c].x, av1[c].y, h[2], l[2]);
        split2(av1[c].z, av1[c].w, h[3], l[3]);
        s16x8 a_hi = __builtin_bit_cast(s16x8, make_uint4(h[0], h[1], h[2], h[3]));
        s16x8 a_lo = __builtin_bit_cast(s16x8, make_uint4(l[0], l[1], l[2], l[3]));
#pragma unroll
        for (int tp = 0; tp < 8; tp++) {
            s16x8 bh = __builtin_bit_cast(s16x8, Wh_s[(c * 8 + tp) * 64 + lane]);
            s16x8 bl = __builtin_bit_cast(s16x8, Wl_s[(c * 8 + tp) * 64 + lane]);
            acc[tp] = __builtin_amdgcn_mfma_f32_16x16x32_bf16(a_hi, bh, acc[tp], 0, 0, 0);
            acc[tp] = __builtin_amdgcn_mfma_f32_16x16x32_bf16(a_lo, bh, acc[tp], 0, 0, 0);
            acc[tp] = __builtin_amdgcn_mfma_f32_16x16x32_bf16(a_hi, bl, acc[tp], 0, 0, 0);
        }
    }
}

// per-subtile epilogue: fused ssum2/wsum2 reduce into LDS + fp16 pair-packed yh store
__device__ inline void epilogue(const f32x4* acc, int nbase, const int* cntSub,
                                _Float16* __restrict__ yh, float* red_ss, float* red_ws,
                                int lane, int w, int N) {
    int fb = lane & 15;
    int rg = lane >> 4;
    int odd = fb & 1;
#pragma unroll
    for (int tp = 0; tp < 8; tp++) {
        int f = tp * 16 + fb;
        float sv = 0.f, wv = 0.f;
#pragma unroll
        for (int r = 0; r < 4; r++) {
            int lr = w * 16 + rg * 4 + r;
            int n = nbase + lr;
            float v = acc[tp][r];
            if (n < N) {
                sv += v * v;
                wv += (float)cntSub[lr] * v * v;
            }
        }
        sv += __shfl_xor(sv, 16, 64); sv += __shfl_xor(sv, 32, 64);
        wv += __shfl_xor(wv, 16, 64); wv += __shfl_xor(wv, 32, 64);
        if (lane < 16) {
            atomicAdd(&red_ss[f], sv);
            atomicAdd(&red_ws[f], wv);
        }
    }
#pragma unroll
    for (int r = 0; r < 4; r++) {
        int n = nbase + w * 16 + rg * 4 + r;
        unsigned hb[8], ob[8], pk[8];
#pragma unroll
        for (int tp = 0; tp < 8; tp++) {
            _Float16 hv = (_Float16)acc[tp][r];
            hb[tp] = (unsigned)__builtin_bit_cast(unsigned short, hv);
        }
#pragma unroll
        for (int tp = 0; tp < 8; tp++) ob[tp] = (unsigned)__shfl_xor((int)hb[tp], 1, 64);
#pragma unroll
        for (int tp = 0; tp < 8; tp++)
            pk[tp] = odd ? (ob[tp] | (hb[tp] << 16)) : (hb[tp] | (ob[tp] << 16));
        if (n < N) {
            unsigned* bp = (unsigned*)(yh + (size_t)n * F + (fb & ~1));
#pragma unroll
            for (int i = 0; i < 4; i++) {
                int tp = 2 * i + odd;
                unsigned v = odd ? pk[2 * i + 1] : pk[2 * i];   // static indices only
                bp[tp * 8] = v;                                  // tp*16 halfs = tp*8 dwords
            }
        }
    }
}

// ---------------------------------------------------------------- K0: pack W into B-fragment order  +  dst histogram
__global__ __launch_bounds__(256) void k_ph(const float* __restrict__ W,
                                            uint4* __restrict__ Wfh, uint4* __restrict__ Wfl,
                                            const int* __restrict__ edge, int* __restrict__ cnt, int E) {
    if (blockIdx.x < 8) {
        int tid = blockIdx.x * 256 + threadIdx.x;   // 0..2047
        int c = tid >> 9;                           // 0..3
        int tp = (tid >> 6) & 7;
        int lane = tid & 63;
        int f = tp * 16 + (lane & 15);
        int k = c * 32 + (lane >> 4) * 8;
        const float* wp = W + f * F + k;
        unsigned h[4], l[4];
#pragma unroll
        for (int p = 0; p < 4; p++) split2(wp[2 * p], wp[2 * p + 1], h[p], l[p]);
        Wfh[tid] = make_uint4(h[0], h[1], h[2], h[3]);
        Wfl[tid] = make_uint4(l[0], l[1], l[2], l[3]);
    } else {
        int stride = (gridDim.x - 8) * 256;
        for (int e = (blockIdx.x - 8) * 256 + threadIdx.x; e < E; e += stride)
            atomicAdd(&cnt[edge[E + e]], 1);
    }
}

// ---------------------------------------------------------------- K2: y = x @ W^T via split-bf16 MFMA
// SINGLE-PHASE 64KB W STAGING (best measured: R6/R7 ~41-43us) + TWO 128-row SUBTILES per
// block sharing it: one barrier-drain + one W-stage per 256 rows (2x amortization).
// Subtile-2's A loads issue right after subtile-1's MFMAs — their ~900cy HBM latency hides
// under subtile-1's epilogue (shfl reductions + LDS atomics + 16 stores).
// All arrays statically indexed; (512,4) keeps VGPR budget 128 (no R8-style forced spill).
__global__ __launch_bounds__(512, 4) void k_gemm(const float* __restrict__ x,
                                                 const uint4* __restrict__ Wfh, const uint4* __restrict__ Wfl,
                                                 const int* __restrict__ cnt, _Float16* __restrict__ yh,
                                                 float* __restrict__ ssum2, float* __restrict__ wsum2, int N) {
    __shared__ uint4 Wh_s[2048];   // 32 KB  B-frags hi
    __shared__ uint4 Wl_s[2048];   // 32 KB  B-frags lo
    __shared__ float red_ss[F];
    __shared__ float red_ws[F];
    __shared__ int cntL[TM];

    int t = threadIdx.x;
    int lane = t & 63;
    int w = t >> 6;
    int n0 = blockIdx.x * TM;

    if (t < F) { red_ss[t] = 0.f; red_ws[t] = 0.f; }
    if (t < TM) { int n = n0 + t; cntL[t] = (n < N) ? cnt[n] : 0; }

    // stage both full fragment planes once (linear dest = wave-uniform base + lane*16)
#pragma unroll
    for (int r = 0; r < 4; r++) {
        int off = (r * 512 + t) * 16;
        load_lds16((const char*)Wfh + off, (char*)Wh_s + off);
    }
#pragma unroll
    for (int r = 0; r < 4; r++) {
        int off = (r * 512 + t) * 16;
        load_lds16((const char*)Wfl + off, (char*)Wl_s + off);
    }

    int fb = lane & 15;
    int rg = lane >> 4;

    // hoist subtile-1's full A row (8 x 16B) — drains together with W staging
    int row1 = n0 + w * 16 + fb;
    if (row1 > N - 1) row1 = N - 1;               // clamp: no fault, masked in epilogue
    const float* xr1 = x + (size_t)row1 * F + rg * 8;
    float4 av0[4], av1[4];
#pragma unroll
    for (int c = 0; c < 4; c++) {
        av0[c] = *(const float4*)(xr1 + c * 32);
        av1[c] = *(const float4*)(xr1 + c * 32 + 4);
    }

    f32x4 acc[8];
#pragma unroll
    for (int i = 0; i < 8; i++) acc[i] = (f32x4){0.f, 0.f, 0.f, 0.f};

    __syncthreads();   // the ONLY drain-coupled barrier: W staging + A1 loads

    // subtile 1 compute
    mfma_tile(av0, av1, Wh_s, Wl_s, lane, acc);

    // issue subtile-2's A loads now: latency hides under subtile-1's epilogue
    int row2 = n0 + 128 + w * 16 + fb;
    if (row2 > N - 1) row2 = N - 1;
    const float* xr2 = x + (size_t)row2 * F + rg * 8;
    float4 bv0[4], bv1[4];
#pragma unroll
    for (int c = 0; c < 4; c++) {
        bv0[c] = *(const float4*)(xr2 + c * 32);
        bv1[c] = *(const float4*)(xr2 + c * 32 + 4);
    }

    // subtile 1 epilogue
    epilogue(acc, n0, cntL, yh, red_ss, red_ws, lane, w, N);

    // subtile 2 compute (same W, no barrier needed — LDS is read-only now)
#pragma unroll
    for (int i = 0; i < 8; i++) acc[i] = (f32x4){0.f, 0.f, 0.f, 0.f};
    mfma_tile(bv0, bv1, Wh_s, Wl_s, lane, acc);

    // subtile 2 epilogue
    epilogue(acc, n0 + 128, cntL + 128, yh, red_ss, red_ws, lane, w, N);

    __syncthreads();
    if (t < F) {
        int bank = (blockIdx.x & 7) * F;
        atomicAdd(&ssum2[bank + t], red_ss[t]);
        atomicAdd(&wsum2[bank + t], red_ws[t]);
    }
}

// ---------------------------------------------------------------- K2b: all global scalar factors (f64)
__global__ __launch_bounds__(256) void k_scalars(const float* __restrict__ W, const float* __restrict__ a,
                                                 const float* __restrict__ ssum2, const float* __restrict__ wsum2,
                                                 float* __restrict__ s_arr, float* __restrict__ asrc,
                                                 float* __restrict__ adst, double* __restrict__ an_out) {
    int t = threadIdx.x;
    double av = (double)a[t];
    av *= av;
#pragma unroll
    for (int off = 32; off; off >>= 1) av += __shfl_down(av, off, 64);
    __shared__ double wred[4];
    if ((t & 63) == 0) wred[t >> 6] = av;
    __syncthreads();
    double an = fmax(sqrt(wred[0] + wred[1] + wred[2] + wred[3]), MIN_NORM_D);
    if (t == 0) an_out[0] = an;

    if (t < F) {
        float ss2f = 0.f, ws2f = 0.f;
#pragma unroll
        for (int b = 0; b < 8; b++) { ss2f += ssum2[b * F + t]; ws2f += wsum2[b * F + t]; }

        double wn2 = 0.0;
        for (int k = 0; k < F; k++) { double w = (double)W[t * F + k]; wn2 += w * w; }
        double wn = fmax(sqrt(wn2), MIN_NORM_D);
        double mxnf = fmax(sqrt((double)ss2f), MIN_NORM_D);
        double tt = tanh(mxnf / wn * atanh_clip(wn));
        double rn = fmax(tt, MIN_NORM_D);
        double pf = (rn > MAXNORM_D) ? MAXNORM_D / rn : 1.0;
        double pn = rn * pf;
        double s = (tt / mxnf) * pf * atanh_clip(pn) / pn;
        s_arr[t] = (float)s;

        double un_s = fmax(s * sqrt((double)DEG * (double)ss2f), MIN_NORM_D);
        double th_s = tanh(un_s);
        double rn2 = fmax(th_s, MIN_NORM_D);
        double pf2 = (rn2 > MAXNORM_D) ? MAXNORM_D / rn2 : 1.0;
        double q_s = s * (th_s / un_s) * pf2;
        asrc[t] = (float)((double)a[t] * q_s);

        double un_d = fmax(s * sqrt((double)ws2f), MIN_NORM_D);
        double th_d = tanh(un_d);
        double rn3 = fmax(th_d, MIN_NORM_D);
        double pf3 = (rn3 > MAXNORM_D) ? MAXNORM_D / rn3 : 1.0;
        double q_d = s * (th_d / un_d) * pf3;
        adst[t] = (float)((double)a[F + t] * q_d);
    }
}

// ---------------------------------------------------------------- K3: P[n]=dot(asrc,y[n,:]) Q[n]=dot(adst,y[n,:])
__global__ __launch_bounds__(256) void k_pq(const _Float16* __restrict__ yh, const float* __restrict__ asrc,
                                            const float* __restrict__ adst, float* __restrict__ P,
                                            float* __restrict__ Q, int N) {
    __shared__ float as4[F], ad4[F];
    int t = threadIdx.x;
    if (t < F) { as4[t] = asrc[t]; ad4[t] = adst[t]; }
    __syncthreads();
    int lane = t & 31;
    float4 av = *(const float4*)&as4[lane * 4];
    float4 bv = *(const float4*)&ad4[lane * 4];
    for (int nb = blockIdx.x * 8; nb < N; nb += gridDim.x * 8) {
        int n = nb + (t >> 5);
        if (n < N) {
            f16x4 hv = *(const f16x4*)&yh[(size_t)n * F + lane * 4];   // 32 lanes x 8B = 256B
            float4 yv = make_float4((float)hv[0], (float)hv[1], (float)hv[2], (float)hv[3]);
            float p = yv.x * av.x + yv.y * av.y + yv.z * av.z + yv.w * av.w;
            float q = yv.x * bv.x + yv.y * bv.y + yv.z * bv.z + yv.w * bv.w;
#pragma unroll
            for (int off = 16; off; off >>= 1) {
                p += __shfl_down(p, off, 32);
                q += __shfl_down(q, off, 32);
            }
            if (lane == 0) { P[n] = p; Q[n] = q; }
        }
    }
}

// ---------------------------------------------------------------- K4: mxn2 = sum_e (P[e/DEG]+Q[dst])^2  (f64)
__global__ __launch_bounds__(256) void k_edge(const int* __restrict__ edge, const float* __restrict__ P,
                                              const float* __restrict__ Q,
                                              double* __restrict__ mxn2, int E) {
    int t = threadIdx.x;
    double local = 0.0;
    for (int e0 = blockIdx.x * 256; e0 < E; e0 += gridDim.x * 256) {
        int e = e0 + t;
        if (e < E) {
            float v = P[e / DEG] + Q[edge[E + e]];
            local += (double)v * (double)v;
        }
    }
#pragma unroll
    for (int off = 32; off; off >>= 1) local += __shfl_down(local, off, 64);
    __shared__ double wsum[4];
    if ((t & 63) == 0) wsum[t >> 6] = local;
    __syncthreads();
    if (t == 0) atomicAdd(mxn2, wsum[0] + wsum[1] + wsum[2] + wsum[3]);
}

// ---------------------------------------------------------------- K5: fused weights + aggregate + epilogue
__global__ __launch_bounds__(256) void k_wagg(const int* __restrict__ edge, const _Float16* __restrict__ yh,
                                              const float* __restrict__ P, const float* __restrict__ Q,
                                              const double* __restrict__ an_p, const double* __restrict__ mxn2_p,
                                              const float* __restrict__ s_arr,
                                              float* __restrict__ out, int N, int E) {
    __shared__ float gS;
    int t = threadIdx.x;
    if (t == 0) {
        double an = an_p[0];
        double mxn = fmax(sqrt(mxn2_p[0]), MIN_NORM_D);
        double t2 = tanh(mxn / an * atanh_clip(an));
        double f2 = t2 / mxn;
        double rnp = fmax(t2, MIN_NORM_D);
        double pfp = (rnp > MAXNORM_D) ? MAXNORM_D / rnp : 1.0;
        double pnp = rnp * pfp;
        gS = (float)(f2 * pfp * atanh_clip(pnp) / pnp);
    }
    __syncthreads();
    float g = gS;

    int lane = t & 63;
    int sub = lane & 7;
    int slot = t >> 3;                 // node slot within block, 0..31
    int gbase = lane & ~7;             // first lane of this 8-lane group

    int n = blockIdx.x * 32 + slot;
    bool active = (n < N);
    int nc = active ? n : N - 1;       // clamp: no fault, store masked

    // phase A: lanes sub<5 compute the edge weight + dst offset
    float w = 0.f; int d = 0;
    if (sub < DEG) {
        int e = nc * DEG + sub;
        int dn = edge[E + e];
        float v = P[nc] + Q[dn];       // == ee_pre[e], same arithmetic as before
        float xg = g * v;
        float gl = 0.5f * xg * (1.f + erff(xg * 0.70710678f));
        w = expf(-gl);
        d = dn << 7;                   // element offset (128 halfs per row)
    }
    float wj[DEG]; int dj[DEG];
#pragma unroll
    for (int j = 0; j < DEG; j++) {
        wj[j] = __shfl(w, gbase + j, 64);
        dj[j] = __shfl(d, gbase + j, 64);
    }
    float rowsum = wj[0] + wj[1] + wj[2] + wj[3] + wj[4];
    float inv = 1.f / rowsum;

    // phase B: fp16 gather + weighted accumulate (same j-order as before)
    float4 acc[4];
#pragma unroll
    for (int p = 0; p < 4; p++) acc[p] = make_float4(0.f, 0.f, 0.f, 0.f);
#pragma unroll
    for (int j = 0; j < DEG; j++) {
        const _Float16* yp = yh + dj[j] + sub * 4;
        float wv = wj[j];
#pragma unroll
        for (int p = 0; p < 4; p++) {
            f16x4 hv = *(const f16x4*)(yp + p * 32);
            acc[p].x = fmaf(wv, (float)hv[0], acc[p].x);
            acc[p].y = fmaf(wv, (float)hv[1], acc[p].y);
            acc[p].z = fmaf(wv, (float)hv[2], acc[p].z);
            acc[p].w = fmaf(wv, (float)hv[3], acc[p].w);
        }
    }

    // epilogue: elu -> expmap0 -> proj (norm reduced over the 8-lane group)
    float4 s4[4];
#pragma unroll
    for (int p = 0; p < 4; p++) s4[p] = *(const float4*)&s_arr[p * 32 + sub * 4];

    float4 el[4];
    float ss = 0.f;
#pragma unroll
    for (int p = 0; p < 4; p++) {
        float h;
        h = s4[p].x * acc[p].x * inv; el[p].x = (h > 0.f) ? h : expm1f(h);
        h = s4[p].y * acc[p].y * inv; el[p].y = (h > 0.f) ? h : expm1f(h);
        h = s4[p].z * acc[p].z * inv; el[p].z = (h > 0.f) ? h : expm1f(h);
        h = s4[p].w * acc[p].w * inv; el[p].w = (h > 0.f) ? h : expm1f(h);
        ss += el[p].x * el[p].x + el[p].y * el[p].y + el[p].z * el[p].z + el[p].w * el[p].w;
    }
    ss += __shfl_xor(ss, 1, 64);
    ss += __shfl_xor(ss, 2, 64);
    ss += __shfl_xor(ss, 4, 64);

    float un = fmaxf(sqrtf(ss), 1e-15f);
    float th = tanhf(un);
    float sc = th / un;                   // expmap0
    float rn = fmaxf(th, 1e-15f);
    if (rn > 0.996f) sc *= 0.996f / rn;   // proj
    if (active) {
        float* op = out + (size_t)n * F + sub * 4;
#pragma unroll
        for (int p = 0; p < 4; p++) {
            float4 o = make_float4(el[p].x * sc, el[p].y * sc, el[p].z * sc, el[p].w * sc);
            *(float4*)(op + p * 32) = o;
        }
    }
}

extern "C" void kernel_launch(void* const* d_in, const int* in_sizes, int n_in,
                              void* d_out, int out_size, void* d_ws, size_t ws_size,
                              hipStream_t stream) {
    const float* x = (const float*)d_in[0];
    const int* edge = (const int*)d_in[1];
    const float* W = (const float*)d_in[2];
    const float* a = (const float*)d_in[3];
    float* out = (float*)d_out;
    int N = in_sizes[0] / F;
    int E = in_sizes[1] / 2;

    char* ws = (char*)d_ws;
    size_t off = 0;
    _Float16* yh = (_Float16*)(ws + off); off += (size_t)N * F * 2;   // fp16 y (only copy)
    uint4* Wfh = (uint4*)(ws + off);     off += 2048 * 16;            // 32 KB B-frag hi
    uint4* Wfl = (uint4*)(ws + off);     off += 2048 * 16;            // 32 KB B-frag lo
    float* P = (float*)(ws + off);       off += (size_t)N * 4;
    float* Q = (float*)(ws + off);       off += (size_t)N * 4;
    char* zbase = ws + off;
    int* cnt = (int*)(ws + off);         off += (size_t)N * 4;
    float* ssum2 = (float*)(ws + off);   off += 8 * F * 4;            // 8 banks
    float* wsum2 = (float*)(ws + off);   off += 8 * F * 4;            // 8 banks
    double* mxn2 = (double*)(ws + off);  off += 8;
    size_t zlen = (size_t)((ws + off) - zbase);
    double* an_p = (double*)(ws + off);  off += 8;
    float* s_arr = (float*)(ws + off);   off += 512;
    float* asrc = (float*)(ws + off);    off += 512;
    float* adst = (float*)(ws + off);    off += 512;

    hipMemsetAsync(zbase, 0, zlen, stream);
    k_ph<<<8 + 1024, 256, 0, stream>>>(W, Wfh, Wfl, edge, cnt, E);
    k_gemm<<<(N + TM - 1) / TM, 512, 0, stream>>>(x, Wfh, Wfl, cnt, yh, ssum2, wsum2, N);
    k_scalars<<<1, 256, 0, stream>>>(W, a, ssum2, wsum2, s_arr, asrc, adst, an_p);
    k_pq<<<2048, 256, 0, stream>>>(yh, asrc, adst, P, Q, N);
    k_edge<<<1024, 256, 0, stream>>>(edge, P, Q, mxn2, E);
    k_wagg<<<(N + 31) / 32, 256, 0, stream>>>(edge, yh, P, Q, an_p, mxn2, s_arr, out, N, E);
}